// Round 1
// baseline (14538.377 us; speedup 1.0000x reference)
//
#include <hip/hip_runtime.h>

// SelfAttention (SAGAN-style) on MI355X.
// B=2, C=64, C8=8, H=W=96, N=9216.  out = gamma * Attn(g,f,h) + x
//   K = f = (Wq/sq) x + bq   (pre-scaled by log2e; softmax in exp2 domain)
//   Q = g = (Wk/sk) x + bk
//   V = h = (Wv/sv) x + bv
// softmax over keys i; head_dim 8 (zero-padded to MFMA K=32), dv=64.

#define N_PIX 9216
#define N_B   2
#define N_C   64

typedef _Float16 half8  __attribute__((ext_vector_type(8)));
typedef _Float16 half4v __attribute__((ext_vector_type(4)));
typedef float    float4v __attribute__((ext_vector_type(4)));

#define LOG2E 1.44269504088896340736f

// ---------------------------------------------------------------- k_sigma
// block 0: Wq (8x64), block 1: Wk (8x64), block 2: Wv (64x64).
// sigma_max via G=W W^T, repeated squaring (normalized), then Rayleigh
// quotient against the ORIGINAL fp32 G (=||W^T u||^2/||u||^2).
__global__ __launch_bounds__(64) void k_sigma(const float* __restrict__ Wq,
                                              const float* __restrict__ Wk,
                                              const float* __restrict__ Wv,
                                              float* __restrict__ sig) {
  __shared__ float G8[8][8];
  __shared__ float Wl[64 * 64];
  __shared__ _Float16 Wh[64 * 80];
  __shared__ _Float16 Gh[64 * 80];
  const int t = threadIdx.x;
  const int mat = blockIdx.x;
  if (mat < 2) {
    const float* W = (mat == 0) ? Wq : Wk;
    const int i = t >> 3, j = t & 7;
    float g = 0.f;
    for (int c = 0; c < 64; ++c) g += W[i * 64 + c] * W[j * 64 + c];
    G8[i][j] = g;
    __syncthreads();
    const int L = t & 7;  // lanes 8..63 mirror rows 0..7 (harmless)
    float G0[8], Gr[8];
    for (int k = 0; k < 8; ++k) { G0[k] = G8[L][k]; Gr[k] = G0[k]; }
    for (int it = 0; it < 8; ++it) {  // -> G^256 direction
      float g2[8] = {0, 0, 0, 0, 0, 0, 0, 0};
      for (int k = 0; k < 8; ++k) {
        float gik = Gr[k];
        for (int jj = 0; jj < 8; ++jj) g2[jj] += gik * __shfl(Gr[jj], k, 64);
      }
      float mx = 0.f;
      for (int jj = 0; jj < 8; ++jj) mx = fmaxf(mx, fabsf(g2[jj]));
      for (int d = 1; d < 8; d <<= 1) mx = fmaxf(mx, __shfl_xor(mx, d, 64));
      float r = 1.f / mx;
      for (int jj = 0; jj < 8; ++jj) Gr[jj] = g2[jj] * r;
    }
    float u = 0.f;
    for (int jj = 0; jj < 8; ++jj) u += Gr[jj];        // u = G^256 * ones
    float y = 0.f;
    for (int k = 0; k < 8; ++k) y += G0[k] * __shfl(u, k, 64);  // y = G u
    float nu = u * y, de = u * u;
    for (int d = 1; d < 8; d <<= 1) { nu += __shfl_xor(nu, d, 64); de += __shfl_xor(de, d, 64); }
    if (t == 0) sig[mat] = sqrtf(nu / de);
  } else {
    for (int idx = t; idx < 4096; idx += 64) Wl[idx] = Wv[idx];
    __syncthreads();
    for (int idx = t; idx < 4096; idx += 64) Wh[(idx >> 6) * 80 + (idx & 63)] = (_Float16)Wl[idx];
    __syncthreads();
    const int lane15 = t & 15, quad = t >> 4;
    // G = W W^T via mfma. B-frag of W^T == row-read of W (same as A-frag).
    half8 fr[4][2];
    for (int rb = 0; rb < 4; ++rb)
      for (int kc = 0; kc < 2; ++kc)
        fr[rb][kc] = *(const half8*)&Wh[(lane15 + 16 * rb) * 80 + 32 * kc + 8 * quad];
    float4v D[4][4];
    for (int mb = 0; mb < 4; ++mb) for (int nb = 0; nb < 4; ++nb) D[mb][nb] = (float4v){0.f, 0.f, 0.f, 0.f};
    for (int kc = 0; kc < 2; ++kc)
      for (int mb = 0; mb < 4; ++mb)
        for (int nb = 0; nb < 4; ++nb)
          D[mb][nb] = __builtin_amdgcn_mfma_f32_16x16x32_f16(fr[mb][kc], fr[nb][kc], D[mb][nb], 0, 0, 0);
    // squarings (G symmetric -> row reads serve both operands)
    for (int it = 0; it < 8; ++it) {
      float mx = 0.f;
      for (int mb = 0; mb < 4; ++mb) for (int nb = 0; nb < 4; ++nb) for (int r = 0; r < 4; ++r)
        mx = fmaxf(mx, fabsf(D[mb][nb][r]));
      for (int d = 1; d < 64; d <<= 1) mx = fmaxf(mx, __shfl_xor(mx, d, 64));
      float rs = 1.f / mx;
      for (int mb = 0; mb < 4; ++mb) for (int nb = 0; nb < 4; ++nb) for (int r = 0; r < 4; ++r)
        Gh[(4 * quad + r + 16 * mb) * 80 + lane15 + 16 * nb] = (_Float16)(D[mb][nb][r] * rs);
      __syncthreads();
      if (it == 7) break;  // Gh = G^128 (normalized)
      for (int rb = 0; rb < 4; ++rb)
        for (int kc = 0; kc < 2; ++kc)
          fr[rb][kc] = *(const half8*)&Gh[(lane15 + 16 * rb) * 80 + 32 * kc + 8 * quad];
      for (int mb = 0; mb < 4; ++mb) for (int nb = 0; nb < 4; ++nb) D[mb][nb] = (float4v){0.f, 0.f, 0.f, 0.f};
      for (int kc = 0; kc < 2; ++kc)
        for (int mb = 0; mb < 4; ++mb)
          for (int nb = 0; nb < 4; ++nb)
            D[mb][nb] = __builtin_amdgcn_mfma_f32_16x16x32_f16(fr[mb][kc], fr[nb][kc], D[mb][nb], 0, 0, 0);
      __syncthreads();
    }
    float u = 0.f;
    for (int c = 0; c < 64; ++c) u += (float)Gh[t * 80 + c];  // u = G^128 * ones (lane t = row t)
    float z = 0.f;  // z_c = sum_i W[i][c] u_i  (lane t = column c)
    for (int i2 = 0; i2 < 64; ++i2) z += Wl[i2 * 64 + t] * __shfl(u, i2, 64);
    float nu = z * z, de = u * u;
    for (int d = 1; d < 64; d <<= 1) { nu += __shfl_xor(nu, d, 64); de += __shfl_xor(de, d, 64); }
    if (t == 0) sig[2] = sqrtf(nu / de);
  }
}

// ---------------------------------------------------------------- k_wconv
// W16[80][64] f16: rows 0-7 = log2e*Wq/sq, 8-15 = Wk/sk, 16-79 = Wv/sv
// b80[80] f32:     0-7 = log2e*bq,         8-15 = bk,    16-79 = bv
__global__ __launch_bounds__(128) void k_wconv(const float* __restrict__ Wq, const float* __restrict__ bq,
                                               const float* __restrict__ Wk, const float* __restrict__ bk,
                                               const float* __restrict__ Wv, const float* __restrict__ bv,
                                               const float* __restrict__ sig,
                                               _Float16* __restrict__ W16, float* __restrict__ b80) {
  const float iq = LOG2E / sig[0], ik = 1.0f / sig[1], iv = 1.0f / sig[2];
  const int t = threadIdx.x;
  for (int idx = t; idx < 80 * 64; idx += 128) {
    const int m = idx >> 6, c = idx & 63;
    float v;
    if (m < 8)       v = Wq[m * 64 + c] * iq;
    else if (m < 16) v = Wk[(m - 8) * 64 + c] * ik;
    else             v = Wv[(m - 16) * 64 + c] * iv;
    W16[idx] = (_Float16)v;
  }
  if (t < 80) {
    float v;
    if (t < 8)       v = bq[t] * LOG2E;
    else if (t < 16) v = bk[t - 8];
    else             v = bv[t - 16];
    b80[t] = v;
  }
}

// ---------------------------------------------------------------- k_fgh
// [80x64] @ [64 x 18432] GEMM via mfma 16x16x32 f16; one wave = 16 columns.
// Outputs: K16[b][i][8], Q16[b][j][8], VT16[b][c][i] (all f16).
__global__ __launch_bounds__(256) void k_fgh(const float* __restrict__ x,
                                             const _Float16* __restrict__ W16,
                                             const float* __restrict__ b80,
                                             _Float16* __restrict__ K16,
                                             _Float16* __restrict__ Q16,
                                             _Float16* __restrict__ VT16) {
  const int wave = threadIdx.x >> 6;
  const int lane = threadIdx.x & 63;
  const int lane15 = lane & 15, quad = lane >> 4;
  const int tile = blockIdx.x * 4 + wave;     // 0..1151
  const int b = tile / 576;
  const int n = (tile % 576) * 16 + lane15;
  // A-frags: W16 rows (m = lane15 + 16*mb), k = 32*kc + 8*quad + j
  half8 wf[5][2];
  for (int mb = 0; mb < 5; ++mb)
    for (int kc = 0; kc < 2; ++kc)
      wf[mb][kc] = *(const half8*)&W16[(lane15 + 16 * mb) * 64 + 32 * kc + 8 * quad];
  // acc init = bias (rows m = 16*mb + 4*quad + r)
  float4v acc[5];
  for (int mb = 0; mb < 5; ++mb) acc[mb] = *(const float4v*)&b80[16 * mb + 4 * quad];
  const float* xb = x + (size_t)b * N_C * N_PIX;
  for (int kc = 0; kc < 2; ++kc) {
    half8 bf;
    for (int j = 0; j < 8; ++j)
      bf[j] = (_Float16)xb[(size_t)(32 * kc + 8 * quad + j) * N_PIX + n];
    for (int mb = 0; mb < 5; ++mb)
      acc[mb] = __builtin_amdgcn_mfma_f32_16x16x32_f16(wf[mb][kc], bf, acc[mb], 0, 0, 0);
  }
  // epilogue: D rows m = 16*mb + 4*quad + r, col = n
  {
    _Float16* dstK = K16 + ((size_t)b * N_PIX + n) * 8;
    _Float16* dstQ = Q16 + ((size_t)b * N_PIX + n) * 8;
    for (int r = 0; r < 4; ++r) {
      const int m = 4 * quad + r;
      const _Float16 v = (_Float16)acc[0][r];
      if (m < 8) dstK[m] = v; else dstQ[m - 8] = v;
    }
  }
  for (int mb = 1; mb < 5; ++mb)
    for (int r = 0; r < 4; ++r) {
      const int c = 4 * quad + r + 16 * (mb - 1);
      VT16[((size_t)b * N_C + c) * N_PIX + n] = (_Float16)acc[mb][r];
    }
}

// ---------------------------------------------------------------- k_attn
// One wave per block; 16 queries per wave; flash loop over 32-key chunks.
__global__ __launch_bounds__(64) void k_attn(const _Float16* __restrict__ K16,
                                             const _Float16* __restrict__ Q16,
                                             const _Float16* __restrict__ VT16,
                                             const float* __restrict__ x,
                                             const float* __restrict__ gamma,
                                             float* __restrict__ out) {
  __shared__ _Float16 P_lds[16 * 40];  // 16 queries x 32 keys, stride 40 halves (16B-aligned rows)
  const int lane = threadIdx.x;
  const int lane15 = lane & 15, quad = lane >> 4;
  const int tile = blockIdx.x;               // 0..1151
  const int b = tile / 576;
  const int j0 = (tile % 576) * 16;
  const float gm = gamma[0];
  const _Float16* Kb = K16 + (size_t)b * N_PIX * 8;
  const _Float16* Vb = VT16 + (size_t)b * N_C * N_PIX;
  // Q frag (B-operand): lane holds Q[j0+lane15][k=8*quad+j]; real k only 0..7
  half8 qf = {};
  if (quad == 0) qf = *(const half8*)(Q16 + ((size_t)b * N_PIX + j0 + lane15) * 8);
  float4v acc[4];
  for (int cb = 0; cb < 4; ++cb) acc[cb] = (float4v){0.f, 0.f, 0.f, 0.f};
  float m_run = -1e30f, l_run = 0.f;
  // prefetch chunk 0
  half8 kf[2][2]; half8 vf[2][4];
  kf[0][0] = (half8){}; kf[0][1] = (half8){};
  if (quad == 0) {
    kf[0][0] = *(const half8*)(Kb + (size_t)(lane15) * 8);
    kf[0][1] = *(const half8*)(Kb + (size_t)(16 + lane15) * 8);
  }
  for (int cb = 0; cb < 4; ++cb)
    vf[0][cb] = *(const half8*)(Vb + (size_t)(lane15 + 16 * cb) * N_PIX + quad * 8);

  const float4v f4z = {0.f, 0.f, 0.f, 0.f};
  for (int i0 = 0; i0 < N_PIX; i0 += 32) {
    const int sl = (i0 >> 5) & 1, sn = sl ^ 1;
    // S = K-tile x Q :  D[i][q], lane: i = i0 + 16*t + 4*quad + r, q = lane15
    float4v s0 = __builtin_amdgcn_mfma_f32_16x16x32_f16(kf[sl][0], qf, f4z, 0, 0, 0);
    float4v s1 = __builtin_amdgcn_mfma_f32_16x16x32_f16(kf[sl][1], qf, f4z, 0, 0, 0);
    // prefetch next chunk early (hide L2 latency behind softmax+PV)
    const int i1 = i0 + 32;
    if (i1 < N_PIX) {
      kf[sn][0] = (half8){}; kf[sn][1] = (half8){};
      if (quad == 0) {
        kf[sn][0] = *(const half8*)(Kb + (size_t)(i1 + lane15) * 8);
        kf[sn][1] = *(const half8*)(Kb + (size_t)(i1 + 16 + lane15) * 8);
      }
      for (int cb = 0; cb < 4; ++cb)
        vf[sn][cb] = *(const half8*)(Vb + (size_t)(lane15 + 16 * cb) * N_PIX + i1 + quad * 8);
    }
    // online softmax over keys (exp2 domain; K pre-scaled by log2e)
    float mc = fmaxf(fmaxf(fmaxf(s0[0], s0[1]), fmaxf(s0[2], s0[3])),
                     fmaxf(fmaxf(s1[0], s1[1]), fmaxf(s1[2], s1[3])));
    mc = fmaxf(mc, __shfl_xor(mc, 16, 64));
    mc = fmaxf(mc, __shfl_xor(mc, 32, 64));
    const float m_new = fmaxf(m_run, mc);
    const float alpha = exp2f(m_run - m_new);
    float p0[4], p1[4], ps = 0.f;
    for (int r = 0; r < 4; ++r) {
      p0[r] = exp2f(s0[r] - m_new);
      p1[r] = exp2f(s1[r] - m_new);
      ps += p0[r] + p1[r];
    }
    ps += __shfl_xor(ps, 16, 64);
    ps += __shfl_xor(ps, 32, 64);
    l_run = alpha * l_run + ps;
    m_run = m_new;
    // rescale accumulator (rows m = 4*quad + r; alpha lives at lane q = m)
    float as[4];
    for (int r = 0; r < 4; ++r) as[r] = __shfl(alpha, 4 * quad + r, 64);
    for (int cb = 0; cb < 4; ++cb)
      for (int r = 0; r < 4; ++r) acc[cb][r] *= as[r];
    // P: C-layout -> A-layout via LDS (same-wave DS ops are in-order)
    half4v h0, h1;
    for (int r = 0; r < 4; ++r) { h0[r] = (_Float16)p0[r]; h1[r] = (_Float16)p1[r]; }
    *(half4v*)&P_lds[lane15 * 40 + 4 * quad] = h0;
    *(half4v*)&P_lds[lane15 * 40 + 16 + 4 * quad] = h1;
    const half8 pf = *(const half8*)&P_lds[lane15 * 40 + 8 * quad];
    // PV: acc[cb] += P x V(cols 16*cb..16*cb+15)
    for (int cb = 0; cb < 4; ++cb)
      acc[cb] = __builtin_amdgcn_mfma_f32_16x16x32_f16(pf, vf[sl][cb], acc[cb], 0, 0, 0);
  }
  // epilogue: out[b][c][j] = gm * acc / l + x
  float li[4];
  for (int r = 0; r < 4; ++r) li[r] = 1.0f / __shfl(l_run, 4 * quad + r, 64);
  const float* xb = x + (size_t)b * N_C * N_PIX;
  float* ob = out + (size_t)b * N_C * N_PIX;
  for (int cb = 0; cb < 4; ++cb) {
    const int c = lane15 + 16 * cb;
    for (int r = 0; r < 4; ++r) {
      const int j = j0 + 4 * quad + r;
      const size_t idx = (size_t)c * N_PIX + j;
      ob[idx] = gm * acc[cb][r] * li[r] + xb[idx];
    }
  }
}

// ---------------------------------------------------------------- launch
extern "C" void kernel_launch(void* const* d_in, const int* in_sizes, int n_in,
                              void* d_out, int out_size, void* d_ws, size_t ws_size,
                              hipStream_t stream) {
  const float* x     = (const float*)d_in[0];
  const float* Wq    = (const float*)d_in[1];
  const float* bq    = (const float*)d_in[2];
  const float* Wk    = (const float*)d_in[3];
  const float* bk    = (const float*)d_in[4];
  const float* Wv    = (const float*)d_in[5];
  const float* bv    = (const float*)d_in[6];
  const float* gamma = (const float*)d_in[7];
  float* out = (float*)d_out;

  char* ws = (char*)d_ws;
  float*    sig  = (float*)ws;                       // 4 floats
  float*    b80  = (float*)(ws + 16);                // 80 floats
  _Float16* W16  = (_Float16*)(ws + 512);            // 80*64 halves
  _Float16* K16  = (_Float16*)(ws + 10752);          // 2*9216*8
  _Float16* Q16  = (_Float16*)(ws + 10752 + 294912); // 2*9216*8
  _Float16* VT16 = (_Float16*)(ws + 10752 + 2 * 294912); // 2*64*9216

  hipLaunchKernelGGL(k_sigma, dim3(3), dim3(64), 0, stream, Wq, Wk, Wv, sig);
  hipLaunchKernelGGL(k_wconv, dim3(1), dim3(128), 0, stream, Wq, bq, Wk, bk, Wv, bv, sig, W16, b80);
  hipLaunchKernelGGL(k_fgh, dim3(288), dim3(256), 0, stream, x, W16, b80, K16, Q16, VT16);
  hipLaunchKernelGGL(k_attn, dim3(1152), dim3(64), 0, stream, K16, Q16, VT16, x, gamma, out);
}

// Round 2
// 280.518 us; speedup vs baseline: 51.8269x; 51.8269x over previous
//
#include <hip/hip_runtime.h>

// SelfAttention (SAGAN-style) on MI355X.
// B=2, C=64, C8=8, H=W=96, N=9216.  out = gamma * Attn(g,f,h) + x
//   K = f = (Wq/sq) x + bq   (pre-scaled by log2e; softmax in exp2 domain)
//   Q = g = (Wk/sk) x + bk
//   V = h = (Wv/sv) x + bv
// softmax over keys i; head_dim 8 (zero-padded to MFMA K=32), dv=64.
//
// R2: k_attn rewritten. R1 pathology: dynamically-indexed private arrays
// (kf[sl]) were demoted to scratch -> 46 GB HBM traffic, 14.5 ms. Now:
// explicit A/B double-buffer with unroll-by-2 (all indices constant), and
// 4-way key-split across the block's 4 waves with LDS flash-merge.

#define N_PIX 9216
#define N_B   2
#define N_C   64

typedef _Float16 half8  __attribute__((ext_vector_type(8)));
typedef _Float16 half4v __attribute__((ext_vector_type(4)));
typedef float    float4v __attribute__((ext_vector_type(4)));

#define LOG2E 1.44269504088896340736f

// ---------------------------------------------------------------- k_sigma
// block 0: Wq (8x64), block 1: Wk (8x64), block 2: Wv (64x64).
// sigma_max via G=W W^T, repeated squaring (normalized), then Rayleigh
// quotient against the ORIGINAL fp32 G (=||W^T u||^2/||u||^2).
__global__ __launch_bounds__(64) void k_sigma(const float* __restrict__ Wq,
                                              const float* __restrict__ Wk,
                                              const float* __restrict__ Wv,
                                              float* __restrict__ sig) {
  __shared__ float G8[8][8];
  __shared__ float Wl[64 * 64];
  __shared__ _Float16 Wh[64 * 80];
  __shared__ _Float16 Gh[64 * 80];
  const int t = threadIdx.x;
  const int mat = blockIdx.x;
  if (mat < 2) {
    const float* W = (mat == 0) ? Wq : Wk;
    const int i = t >> 3, j = t & 7;
    float g = 0.f;
    for (int c = 0; c < 64; ++c) g += W[i * 64 + c] * W[j * 64 + c];
    G8[i][j] = g;
    __syncthreads();
    const int L = t & 7;  // lanes 8..63 mirror rows 0..7 (harmless)
    float G0[8], Gr[8];
    for (int k = 0; k < 8; ++k) { G0[k] = G8[L][k]; Gr[k] = G0[k]; }
    for (int it = 0; it < 8; ++it) {  // -> G^256 direction
      float g2[8] = {0, 0, 0, 0, 0, 0, 0, 0};
      for (int k = 0; k < 8; ++k) {
        float gik = Gr[k];
        for (int jj = 0; jj < 8; ++jj) g2[jj] += gik * __shfl(Gr[jj], k, 64);
      }
      float mx = 0.f;
      for (int jj = 0; jj < 8; ++jj) mx = fmaxf(mx, fabsf(g2[jj]));
      for (int d = 1; d < 8; d <<= 1) mx = fmaxf(mx, __shfl_xor(mx, d, 64));
      float r = 1.f / mx;
      for (int jj = 0; jj < 8; ++jj) Gr[jj] = g2[jj] * r;
    }
    float u = 0.f;
    for (int jj = 0; jj < 8; ++jj) u += Gr[jj];        // u = G^256 * ones
    float y = 0.f;
    for (int k = 0; k < 8; ++k) y += G0[k] * __shfl(u, k, 64);  // y = G u
    float nu = u * y, de = u * u;
    for (int d = 1; d < 8; d <<= 1) { nu += __shfl_xor(nu, d, 64); de += __shfl_xor(de, d, 64); }
    if (t == 0) sig[mat] = sqrtf(nu / de);
  } else {
    for (int idx = t; idx < 4096; idx += 64) Wl[idx] = Wv[idx];
    __syncthreads();
    for (int idx = t; idx < 4096; idx += 64) Wh[(idx >> 6) * 80 + (idx & 63)] = (_Float16)Wl[idx];
    __syncthreads();
    const int lane15 = t & 15, quad = t >> 4;
    // G = W W^T via mfma. B-frag of W^T == row-read of W (same as A-frag).
    half8 fr[4][2];
    for (int rb = 0; rb < 4; ++rb)
      for (int kc = 0; kc < 2; ++kc)
        fr[rb][kc] = *(const half8*)&Wh[(lane15 + 16 * rb) * 80 + 32 * kc + 8 * quad];
    float4v D[4][4];
    for (int mb = 0; mb < 4; ++mb) for (int nb = 0; nb < 4; ++nb) D[mb][nb] = (float4v){0.f, 0.f, 0.f, 0.f};
    for (int kc = 0; kc < 2; ++kc)
      for (int mb = 0; mb < 4; ++mb)
        for (int nb = 0; nb < 4; ++nb)
          D[mb][nb] = __builtin_amdgcn_mfma_f32_16x16x32_f16(fr[mb][kc], fr[nb][kc], D[mb][nb], 0, 0, 0);
    // squarings (G symmetric -> row reads serve both operands)
    for (int it = 0; it < 8; ++it) {
      float mx = 0.f;
      for (int mb = 0; mb < 4; ++mb) for (int nb = 0; nb < 4; ++nb) for (int r = 0; r < 4; ++r)
        mx = fmaxf(mx, fabsf(D[mb][nb][r]));
      for (int d = 1; d < 64; d <<= 1) mx = fmaxf(mx, __shfl_xor(mx, d, 64));
      float rs = 1.f / mx;
      for (int mb = 0; mb < 4; ++mb) for (int nb = 0; nb < 4; ++nb) for (int r = 0; r < 4; ++r)
        Gh[(4 * quad + r + 16 * mb) * 80 + lane15 + 16 * nb] = (_Float16)(D[mb][nb][r] * rs);
      __syncthreads();
      if (it == 7) break;  // Gh = G^128 (normalized)
      for (int rb = 0; rb < 4; ++rb)
        for (int kc = 0; kc < 2; ++kc)
          fr[rb][kc] = *(const half8*)&Gh[(lane15 + 16 * rb) * 80 + 32 * kc + 8 * quad];
      for (int mb = 0; mb < 4; ++mb) for (int nb = 0; nb < 4; ++nb) D[mb][nb] = (float4v){0.f, 0.f, 0.f, 0.f};
      for (int kc = 0; kc < 2; ++kc)
        for (int mb = 0; mb < 4; ++mb)
          for (int nb = 0; nb < 4; ++nb)
            D[mb][nb] = __builtin_amdgcn_mfma_f32_16x16x32_f16(fr[mb][kc], fr[nb][kc], D[mb][nb], 0, 0, 0);
      __syncthreads();
    }
    float u = 0.f;
    for (int c = 0; c < 64; ++c) u += (float)Gh[t * 80 + c];  // u = G^128 * ones (lane t = row t)
    float z = 0.f;  // z_c = sum_i W[i][c] u_i  (lane t = column c)
    for (int i2 = 0; i2 < 64; ++i2) z += Wl[i2 * 64 + t] * __shfl(u, i2, 64);
    float nu = z * z, de = u * u;
    for (int d = 1; d < 64; d <<= 1) { nu += __shfl_xor(nu, d, 64); de += __shfl_xor(de, d, 64); }
    if (t == 0) sig[2] = sqrtf(nu / de);
  }
}

// ---------------------------------------------------------------- k_wconv
// W16[80][64] f16: rows 0-7 = log2e*Wq/sq, 8-15 = Wk/sk, 16-79 = Wv/sv
// b80[80] f32:     0-7 = log2e*bq,         8-15 = bk,    16-79 = bv
__global__ __launch_bounds__(128) void k_wconv(const float* __restrict__ Wq, const float* __restrict__ bq,
                                               const float* __restrict__ Wk, const float* __restrict__ bk,
                                               const float* __restrict__ Wv, const float* __restrict__ bv,
                                               const float* __restrict__ sig,
                                               _Float16* __restrict__ W16, float* __restrict__ b80) {
  const float iq = LOG2E / sig[0], ik = 1.0f / sig[1], iv = 1.0f / sig[2];
  const int t = threadIdx.x;
  for (int idx = t; idx < 80 * 64; idx += 128) {
    const int m = idx >> 6, c = idx & 63;
    float v;
    if (m < 8)       v = Wq[m * 64 + c] * iq;
    else if (m < 16) v = Wk[(m - 8) * 64 + c] * ik;
    else             v = Wv[(m - 16) * 64 + c] * iv;
    W16[idx] = (_Float16)v;
  }
  if (t < 80) {
    float v;
    if (t < 8)       v = bq[t] * LOG2E;
    else if (t < 16) v = bk[t - 8];
    else             v = bv[t - 16];
    b80[t] = v;
  }
}

// ---------------------------------------------------------------- k_fgh
// [80x64] @ [64 x 18432] GEMM via mfma 16x16x32 f16; one wave = 16 columns.
// Outputs: K16[b][i][8], Q16[b][j][8], VT16[b][c][i] (all f16).
__global__ __launch_bounds__(256) void k_fgh(const float* __restrict__ x,
                                             const _Float16* __restrict__ W16,
                                             const float* __restrict__ b80,
                                             _Float16* __restrict__ K16,
                                             _Float16* __restrict__ Q16,
                                             _Float16* __restrict__ VT16) {
  const int wave = threadIdx.x >> 6;
  const int lane = threadIdx.x & 63;
  const int lane15 = lane & 15, quad = lane >> 4;
  const int tile = blockIdx.x * 4 + wave;     // 0..1151
  const int b = tile / 576;
  const int n = (tile % 576) * 16 + lane15;
  // A-frags: W16 rows (m = lane15 + 16*mb), k = 32*kc + 8*quad + j
  half8 wf[5][2];
  for (int mb = 0; mb < 5; ++mb)
    for (int kc = 0; kc < 2; ++kc)
      wf[mb][kc] = *(const half8*)&W16[(lane15 + 16 * mb) * 64 + 32 * kc + 8 * quad];
  // acc init = bias (rows m = 16*mb + 4*quad + r)
  float4v acc[5];
  for (int mb = 0; mb < 5; ++mb) acc[mb] = *(const float4v*)&b80[16 * mb + 4 * quad];
  const float* xb = x + (size_t)b * N_C * N_PIX;
  for (int kc = 0; kc < 2; ++kc) {
    half8 bf;
    for (int j = 0; j < 8; ++j)
      bf[j] = (_Float16)xb[(size_t)(32 * kc + 8 * quad + j) * N_PIX + n];
    for (int mb = 0; mb < 5; ++mb)
      acc[mb] = __builtin_amdgcn_mfma_f32_16x16x32_f16(wf[mb][kc], bf, acc[mb], 0, 0, 0);
  }
  // epilogue: D rows m = 16*mb + 4*quad + r, col = n
  {
    _Float16* dstK = K16 + ((size_t)b * N_PIX + n) * 8;
    _Float16* dstQ = Q16 + ((size_t)b * N_PIX + n) * 8;
    for (int r = 0; r < 4; ++r) {
      const int m = 4 * quad + r;
      const _Float16 v = (_Float16)acc[0][r];
      if (m < 8) dstK[m] = v; else dstQ[m - 8] = v;
    }
  }
  for (int mb = 1; mb < 5; ++mb)
    for (int r = 0; r < 4; ++r) {
      const int c = 4 * quad + r + 16 * (mb - 1);
      VT16[((size_t)b * N_C + c) * N_PIX + n] = (_Float16)acc[mb][r];
    }
}

// ---------------------------------------------------------------- k_attn
// Block = 256 threads = 4 waves, one 16-query tile; wave w handles keys
// [w*2304,(w+1)*2304) flash-style, then LDS merge of (m,l,acc) partials.
// All private buffers constant-indexed (A/B double-buffer, unroll-by-2).

__device__ __forceinline__ void attn_chunk(
    const int i1, const bool do_pref,
    half8 (&kf)[2], half8 (&vf)[4],          // current chunk frags
    half8 (&kfn)[2], half8 (&vfn)[4],        // prefetch destination
    const half8 qf, float4v (&acc)[4],
    float& m_run, float& l_run,
    const _Float16* __restrict__ Kb, const _Float16* __restrict__ Vb,
    _Float16* Pl, const int lane15, const int quad) {
  const float4v f4z = {0.f, 0.f, 0.f, 0.f};
  // S = K-tile x Q :  D[i][q], lane: i = 16*t + 4*quad + r, q = lane15
  float4v s0 = __builtin_amdgcn_mfma_f32_16x16x32_f16(kf[0], qf, f4z, 0, 0, 0);
  float4v s1 = __builtin_amdgcn_mfma_f32_16x16x32_f16(kf[1], qf, f4z, 0, 0, 0);
  if (do_pref) {  // issue next-chunk loads early; hide L2 latency behind softmax
    kfn[0] = (half8){}; kfn[1] = (half8){};
    if (quad == 0) {
      kfn[0] = *(const half8*)(Kb + (size_t)(i1 + lane15) * 8);
      kfn[1] = *(const half8*)(Kb + (size_t)(i1 + 16 + lane15) * 8);
    }
    for (int cb = 0; cb < 4; ++cb)
      vfn[cb] = *(const half8*)(Vb + (size_t)(lane15 + 16 * cb) * N_PIX + i1 + quad * 8);
  }
  // online softmax over keys (exp2 domain; K pre-scaled by log2e)
  float mc = fmaxf(fmaxf(fmaxf(s0[0], s0[1]), fmaxf(s0[2], s0[3])),
                   fmaxf(fmaxf(s1[0], s1[1]), fmaxf(s1[2], s1[3])));
  mc = fmaxf(mc, __shfl_xor(mc, 16, 64));
  mc = fmaxf(mc, __shfl_xor(mc, 32, 64));
  const float m_new = fmaxf(m_run, mc);
  const float alpha = exp2f(m_run - m_new);
  float p0[4], p1[4], ps = 0.f;
  for (int r = 0; r < 4; ++r) {
    p0[r] = exp2f(s0[r] - m_new);
    p1[r] = exp2f(s1[r] - m_new);
    ps += p0[r] + p1[r];
  }
  ps += __shfl_xor(ps, 16, 64);
  ps += __shfl_xor(ps, 32, 64);
  l_run = alpha * l_run + ps;
  m_run = m_new;
  // rescale accumulator (rows m = 4*quad + r; alpha lives at lane q = m)
  float as[4];
  for (int r = 0; r < 4; ++r) as[r] = __shfl(alpha, 4 * quad + r, 64);
  for (int cb = 0; cb < 4; ++cb)
    for (int r = 0; r < 4; ++r) acc[cb][r] *= as[r];
  // P: C-layout -> A-layout via LDS (same-wave DS ops are in-order)
  half4v h0, h1;
  for (int r = 0; r < 4; ++r) { h0[r] = (_Float16)p0[r]; h1[r] = (_Float16)p1[r]; }
  *(half4v*)&Pl[lane15 * 40 + 4 * quad] = h0;
  *(half4v*)&Pl[lane15 * 40 + 16 + 4 * quad] = h1;
  const half8 pf = *(const half8*)&Pl[lane15 * 40 + 8 * quad];
  // PV: acc[cb] += P x V(cols 16*cb..16*cb+15)
  for (int cb = 0; cb < 4; ++cb)
    acc[cb] = __builtin_amdgcn_mfma_f32_16x16x32_f16(pf, vf[cb], acc[cb], 0, 0, 0);
}

__global__ __launch_bounds__(256) void k_attn(const _Float16* __restrict__ K16,
                                              const _Float16* __restrict__ Q16,
                                              const _Float16* __restrict__ VT16,
                                              const float* __restrict__ x,
                                              const float* __restrict__ gamma,
                                              float* __restrict__ out) {
  __shared__ _Float16 P_lds[4][16 * 40];   // per-wave P transpose buffer
  __shared__ float Lacc[4][64][17];        // +1 pad: stride-16 would be 32-way conflict
  __shared__ float Lm[4][16], Ll[4][16];
  const int wave = threadIdx.x >> 6;
  const int lane = threadIdx.x & 63;
  const int lane15 = lane & 15, quad = lane >> 4;
  const int tile = blockIdx.x;               // 0..1151
  const int b = tile / 576;
  const int j0 = (tile % 576) * 16;
  const float gm = gamma[0];
  const _Float16* Kb = K16 + (size_t)b * N_PIX * 8;
  const _Float16* Vb = VT16 + (size_t)b * N_C * N_PIX;
  _Float16* Pl = P_lds[wave];
  const int kbeg = wave * (N_PIX / 4);
  const int kend = kbeg + (N_PIX / 4);
  // Q frag (B-operand): lane holds Q[j0+lane15][k=8*quad+j]; real k only 0..7
  half8 qf = {};
  if (quad == 0) qf = *(const half8*)(Q16 + ((size_t)b * N_PIX + j0 + lane15) * 8);
  float4v acc[4];
  for (int cb = 0; cb < 4; ++cb) acc[cb] = (float4v){0.f, 0.f, 0.f, 0.f};
  float m_run = -1e30f, l_run = 0.f;
  // preload chunk 0 into buffer A (explicit names -> registers, never scratch)
  half8 kA[2], kB[2], vA[4], vB[4];
  kA[0] = (half8){}; kA[1] = (half8){};
  if (quad == 0) {
    kA[0] = *(const half8*)(Kb + (size_t)(kbeg + lane15) * 8);
    kA[1] = *(const half8*)(Kb + (size_t)(kbeg + 16 + lane15) * 8);
  }
  for (int cb = 0; cb < 4; ++cb)
    vA[cb] = *(const half8*)(Vb + (size_t)(lane15 + 16 * cb) * N_PIX + kbeg + quad * 8);
  for (int i0 = kbeg; i0 < kend; i0 += 64) {
    attn_chunk(i0 + 32, true, kA, vA, kB, vB, qf, acc, m_run, l_run, Kb, Vb, Pl, lane15, quad);
    attn_chunk(i0 + 64, (i0 + 64) < kend, kB, vB, kA, vA, qf, acc, m_run, l_run, Kb, Vb, Pl, lane15, quad);
  }
  // ---- flash merge of the 4 waves' partials through LDS
  if (quad == 0) { Lm[wave][lane15] = m_run; Ll[wave][lane15] = l_run; }
  for (int cb = 0; cb < 4; ++cb)
    for (int r = 0; r < 4; ++r) Lacc[wave][lane][4 * cb + r] = acc[cb][r];
  __syncthreads();
  // wave w owns channel block cb=w: c = lane15 + 16*w, queries j = 4*quad+r
  const int c = lane15 + 16 * wave;
  const float* xb = x + (size_t)b * N_C * N_PIX;
  float* ob = out + (size_t)b * N_C * N_PIX;
  for (int r = 0; r < 4; ++r) {
    const int jq = 4 * quad + r;
    const float m0 = Lm[0][jq], m1 = Lm[1][jq], m2 = Lm[2][jq], m3 = Lm[3][jq];
    const float ms = fmaxf(fmaxf(m0, m1), fmaxf(m2, m3));
    const float s0 = exp2f(m0 - ms), s1 = exp2f(m1 - ms), s2 = exp2f(m2 - ms), s3 = exp2f(m3 - ms);
    const float lst = Ll[0][jq] * s0 + Ll[1][jq] * s1 + Ll[2][jq] * s2 + Ll[3][jq] * s3;
    const float osum = Lacc[0][lane][4 * wave + r] * s0 + Lacc[1][lane][4 * wave + r] * s1
                     + Lacc[2][lane][4 * wave + r] * s2 + Lacc[3][lane][4 * wave + r] * s3;
    const int j = j0 + jq;
    const size_t idx = (size_t)c * N_PIX + j;
    ob[idx] = gm * osum / lst + xb[idx];
  }
}

// ---------------------------------------------------------------- launch
extern "C" void kernel_launch(void* const* d_in, const int* in_sizes, int n_in,
                              void* d_out, int out_size, void* d_ws, size_t ws_size,
                              hipStream_t stream) {
  const float* x     = (const float*)d_in[0];
  const float* Wq    = (const float*)d_in[1];
  const float* bq    = (const float*)d_in[2];
  const float* Wk    = (const float*)d_in[3];
  const float* bk    = (const float*)d_in[4];
  const float* Wv    = (const float*)d_in[5];
  const float* bv    = (const float*)d_in[6];
  const float* gamma = (const float*)d_in[7];
  float* out = (float*)d_out;

  char* ws = (char*)d_ws;
  float*    sig  = (float*)ws;                       // 4 floats
  float*    b80  = (float*)(ws + 16);                // 80 floats
  _Float16* W16  = (_Float16*)(ws + 512);            // 80*64 halves
  _Float16* K16  = (_Float16*)(ws + 10752);          // 2*9216*8
  _Float16* Q16  = (_Float16*)(ws + 10752 + 294912); // 2*9216*8
  _Float16* VT16 = (_Float16*)(ws + 10752 + 2 * 294912); // 2*64*9216

  hipLaunchKernelGGL(k_sigma, dim3(3), dim3(64), 0, stream, Wq, Wk, Wv, sig);
  hipLaunchKernelGGL(k_wconv, dim3(1), dim3(128), 0, stream, Wq, bq, Wk, bk, Wv, bv, sig, W16, b80);
  hipLaunchKernelGGL(k_fgh, dim3(288), dim3(256), 0, stream, x, W16, b80, K16, Q16, VT16);
  hipLaunchKernelGGL(k_attn, dim3(1152), dim3(256), 0, stream, K16, Q16, VT16, x, gamma, out);
}